// Round 5
// baseline (328.152 us; speedup 1.0000x reference)
//
#include <hip/hip_runtime.h>

typedef unsigned short u16;
typedef __bf16 bf16x8 __attribute__((ext_vector_type(8)));
typedef float f32x4 __attribute__((ext_vector_type(4)));

#define HH  56
#define WW  56
#define HW  3136      // 56*56
#define CC  256
#define NB  8
#define CKP 2048      // c*7 padded to c*8 so each channel's 7 taps are one 16B chunk
#define KS1 4         // split-K factor GEMM1 (49 iters -> 12/12/12/13)
#define KS2 2         // split-K factor GEMM2 (32 iters -> 16/16)

// round-to-nearest-even fp32 -> bf16 (bit pattern)
__device__ __forceinline__ u16 f2bf(float f) {
  unsigned int u = __float_as_uint(f);
  u += 0x7fffu + ((u >> 16) & 1u);
  return (u16)(u >> 16);
}
__device__ __forceinline__ float bf2f(u16 v) {
  return __uint_as_float((unsigned)v << 16);
}

// async global->LDS, 16B per lane; LDS dest is wave-uniform base + lane*16
__device__ __forceinline__ void lds_load16(const void* g, void* l) {
  __builtin_amdgcn_global_load_lds(
      (const __attribute__((address_space(1))) void*)g,
      (__attribute__((address_space(3))) void*)l, 16, 0, 0);
}

// ---------------------------------------------------------------------------
// pass1: t1b = bf16(p1w * x), xb = bf16(x).  Fully coalesced float4 reads.
// grid = N*C*HW/4/256 = 6272 blocks
// ---------------------------------------------------------------------------
__global__ void pass1(const float* __restrict__ x, const float* __restrict__ p1w,
                      u16* __restrict__ t1b, u16* __restrict__ xb) {
  int i = blockIdx.x * 256 + threadIdx.x;        // over N*C*HW/4
  int cw = i % (CC * HW / 4);                    // p1w broadcast over n
  float4 xv = ((const float4*)x)[i];
  float4 wv = ((const float4*)p1w)[cw];
  uint2 xo = make_uint2((unsigned)f2bf(xv.x) | ((unsigned)f2bf(xv.y) << 16),
                        (unsigned)f2bf(xv.z) | ((unsigned)f2bf(xv.w) << 16));
  ((uint2*)xb)[i] = xo;
  uint2 to = make_uint2((unsigned)f2bf(xv.x * wv.x) | ((unsigned)f2bf(xv.y * wv.y) << 16),
                        (unsigned)f2bf(xv.z * wv.z) | ((unsigned)f2bf(xv.w * wv.w) << 16));
  ((uint2*)t1b)[i] = to;
}

// ---------------------------------------------------------------------------
// pass2 (vectorized, 8 p per thread):
//   t5[n][j*8+k][p] = bf16(t1[n,j,p] - t1[n,(j-1)%C, h, w+k-3 (0-pad)])
// Loads: 1 uint4 row chunk + up to 3 uint4 tap chunks; stores 7 uint4.
// pad rows j*8+7 untouched (finite poison; their t7 columns are zeroed).
// grid = N*C*HW/8/256 = 3136
// ---------------------------------------------------------------------------
__global__ void pass2(const u16* __restrict__ t1b, u16* __restrict__ t5) {
  int idx = blockIdx.x * 256 + threadIdx.x;   // over NB*CC*(HW/8)
  int pc  = idx % (HW / 8);
  int rem = idx / (HW / 8);                   // n*C + j
  int j   = rem & (CC - 1);
  int n   = rem >> 8;
  int p0  = pc * 8;
  int h   = p0 / WW;
  int w0  = p0 - h * WW;                      // multiple of 8
  int jm  = (j + CC - 1) & (CC - 1);
  const u16* t1n = t1b + (long)(n * CC) * HW;

  u16 a[8];
  *(uint4*)a = *(const uint4*)&t1n[(long)j * HW + p0];
  const u16* rowm = t1n + (long)jm * HW + h * WW;
  u16 b[24];
  *(uint4*)&b[8] = *(const uint4*)&rowm[w0];
  if (w0 > 0)  *(uint4*)&b[0]  = *(const uint4*)&rowm[w0 - 8];
  else { b[5] = 0; b[6] = 0; b[7] = 0; }      // only positions 5..7 are used
  if (w0 < WW - 8) *(uint4*)&b[16] = *(const uint4*)&rowm[w0 + 8];
  else { b[16] = 0; b[17] = 0; b[18] = 0; }   // only positions 16..18 used

  float af[8];
#pragma unroll
  for (int i = 0; i < 8; ++i) af[i] = bf2f(a[i]);
  float bf[14];                               // window positions 5..18
#pragma unroll
  for (int i = 0; i < 14; ++i) bf[i] = bf2f(b[i + 5]);

  u16* out = t5 + ((long)n * CKP + j * 8) * HW + p0;
#pragma unroll
  for (int k = 0; k < 7; ++k) {
    u16 v[8];
#pragma unroll
    for (int i = 0; i < 8; ++i) v[i] = f2bf(af[i] - bf[i + k]);
    *(uint4*)&out[(long)k * HW] = make_uint4(
        v[0] | ((unsigned)v[1] << 16), v[2] | ((unsigned)v[3] << 16),
        v[4] | ((unsigned)v[5] << 16), v[6] | ((unsigned)v[7] << 16));
  }
}

// ---------------------------------------------------------------------------
// pass3 (j-chunked LDS transpose): t6T[n][p][j*8+k] =
//   bf16(x[n,j,p] + t1[n,(j-1)%C,(h-1)%56,((w+1)%56)+k-3]),  slot 7 = 0.
// Block = 16 p-values; 4 chunks of 64 channels; tile 16x(512+8) u16 = 16.6 KB.
// Phase A: 16 lanes along p -> full 64B x lines.  Phase B: 256B-run writes.
// grid = (HW/16=196, NB)
// ---------------------------------------------------------------------------
#define P3P  16
#define P3S  (512 + 8)          // chunk-tile row stride in u16 (bank rot 4/row)
__global__ __launch_bounds__(256)
void pass3(const float* __restrict__ x, const u16* __restrict__ t1b,
           u16* __restrict__ t6T) {
  __shared__ u16 tile[P3P * P3S];   // 16.6 KB
  const int n  = blockIdx.y;
  const int p0 = blockIdx.x * P3P;
  const int t  = threadIdx.x;

  const int pl = t & 15, js = t >> 4;     // phase A mapping
  const int p  = p0 + pl;
  const int h  = p / WW, w = p - h * WW;
  const int h2 = (h + HH - 1) % HH;       // roll +1 on h: source row h-1
  const int w2 = (w + 1) % WW;            // roll -1 on w: source col w+1
  const float* xn = x   + (long)n * CC * HW;
  const u16* t1n  = t1b + (long)n * CC * HW;

  const int pp = t >> 4, cl = t & 15;     // phase B mapping

  for (int jc = 0; jc < 4; ++jc) {
    // ---- phase A: compute 64 channels into the tile ----
#pragma unroll
    for (int jo = 0; jo < 4; ++jo) {
      const int j  = jc * 64 + jo * 16 + js;
      const int jm = (j + CC - 1) & (CC - 1);
      const float xv  = xn[(long)j * HW + p];
      const u16* rowm = t1n + (long)jm * HW + h2 * WW;
      u16 v[8];
#pragma unroll
      for (int k = 0; k < 7; ++k) {
        int tap = w2 + k - 3;
        float t4v = ((unsigned)tap < (unsigned)WW) ? bf2f(rowm[tap]) : 0.f;
        v[k] = f2bf(xv + t4v);
      }
      v[7] = 0;
      *(uint4*)&tile[pl * P3S + (jo * 16 + js) * 8] = make_uint4(
          v[0] | ((unsigned)v[1] << 16), v[2] | ((unsigned)v[3] << 16),
          v[4] | ((unsigned)v[5] << 16), v[6] | ((unsigned)v[7] << 16));
    }
    __syncthreads();
    // ---- phase B: coalesced write-out of this chunk ----
    u16* outp = t6T + ((long)(n * HW + p0 + pp)) * CKP + jc * 512;
    const u16* srcp = &tile[pp * P3S];
#pragma unroll
    for (int ci = 0; ci < 4; ++ci) {
      int chunk = ci * 16 + cl;           // 64 chunks of 8 u16 per p-row
      *(uint4*)&outp[chunk * 8] = *(const uint4*)&srcp[chunk * 8];
    }
    __syncthreads();
  }
}

// ---------------------------------------------------------------------------
// Split-K NT GEMM, bf16 MFMA 16x16x32, 128x128 tile, BK=64, global_load_lds,
// XOR chunk swizzle.  Split-K blocks accumulate via fp32 global atomicAdd
// into a pre-zeroed buffer (no partials / reduce kernels).
// IS1: A=xb(256x3136) B=t5(2048x3136) -> c1 fp32 (unscaled).
// !IS1: A=t7(256x2048) B=t6T(3136x2048) -> d_out fp32 (scaled), col guard.
// grid = (2, N/128, NB*KS)
// ---------------------------------------------------------------------------
template <int IS1, int KS>
__global__ __launch_bounds__(256)
void gemm_nt(const u16* __restrict__ A, const u16* __restrict__ B,
             float* __restrict__ Cp) {
  constexpr int  LDA = IS1 ? HW : CKP;
  constexpr int  LDB = IS1 ? HW : CKP;
  constexpr int  NIT = IS1 ? HW / 64 : CKP / 64;   // 49 : 32 K-iterations
  constexpr int  LDC = IS1 ? CKP : HW;
  constexpr long sA  = IS1 ? (long)CC * HW : (long)CC * CKP;
  constexpr long sB  = IS1 ? (long)CKP * HW : (long)HW * CKP;
  constexpr long sC  = IS1 ? (long)CC * CKP : (long)CC * HW;

  __shared__ u16 As[128 * 64];
  __shared__ u16 Bs[128 * 64];

  const int z  = blockIdx.z;
  const int nb = z / KS, ks = z % KS;
  const int it0 = NIT * ks / KS, it1 = NIT * (ks + 1) / KS;
  const u16* Ab = A + nb * sA;
  const u16* Bb = B + nb * sB;
  const int m0 = blockIdx.x * 128, n0 = blockIdx.y * 128;
  const int t = threadIdx.x;
  const int lane = t & 63, wave = t >> 6;
  const int wm = wave & 1, wn = wave >> 1;     // 2x2 waves, 64x64 each
  const int lm = lane & 15, quad = lane >> 4;

  f32x4 acc[4][4];
#pragma unroll
  for (int a = 0; a < 4; ++a)
#pragma unroll
    for (int b = 0; b < 4; ++b) acc[a][b] = (f32x4)0.0f;

  // staging geometry: 1024 chunks of 16B per tile, 4 per thread.
  int rowc[4], colc[4];
#pragma unroll
  for (int ci = 0; ci < 4; ++ci) {
    int c = t + ci * 256;
    rowc[ci] = c >> 3;
    colc[ci] = ((c & 7) ^ (rowc[ci] & 7)) * 8;   // XOR swizzle breaks bank aliasing
  }

  for (int it = it0; it < it1; ++it) {
    const int k0 = it * 64;
#pragma unroll
    for (int ci = 0; ci < 4; ++ci) {
      int c = t + ci * 256;
      lds_load16(Ab + (long)(m0 + rowc[ci]) * LDA + k0 + colc[ci], &As[c * 8]);
      int br = n0 + rowc[ci];
      if (!IS1) br = br < (HW - 1) ? br : (HW - 1);   // clamp rows past 3135
      lds_load16(Bb + (long)br * LDB + k0 + colc[ci], &Bs[c * 8]);
    }
    __syncthreads();
#pragma unroll
    for (int kk = 0; kk < 2; ++kk) {
      const int phys = ((kk * 4 + quad) ^ (lm & 7)) * 8;  // swizzled chunk, elems
      bf16x8 af[4], bv[4];
#pragma unroll
      for (int mi = 0; mi < 4; ++mi)
        af[mi] = *(const bf16x8*)&As[(wm * 64 + mi * 16 + lm) * 64 + phys];
#pragma unroll
      for (int ni = 0; ni < 4; ++ni)
        bv[ni] = *(const bf16x8*)&Bs[(wn * 64 + ni * 16 + lm) * 64 + phys];
#pragma unroll
      for (int mi = 0; mi < 4; ++mi)
#pragma unroll
        for (int ni = 0; ni < 4; ++ni)
          acc[mi][ni] = __builtin_amdgcn_mfma_f32_16x16x32_bf16(
              af[mi], bv[ni], acc[mi][ni], 0, 0, 0);
    }
    __syncthreads();
  }

  // epilogue: fp32 atomic accumulate; C/D layout: col=lane&15, row=quad*4+reg
  const float scale = IS1 ? 1.0f : 0.023622783f;   // gemm2: 1/sqrt(1792)
  float* Cb = Cp + (long)nb * sC;
#pragma unroll
  for (int mi = 0; mi < 4; ++mi)
#pragma unroll
    for (int ni = 0; ni < 4; ++ni) {
      int rb = m0 + wm * 64 + mi * 16 + quad * 4;
      int cg = n0 + wn * 64 + ni * 16 + lm;
      if (IS1 || cg < HW) {
#pragma unroll
        for (int r = 0; r < 4; ++r)
          atomicAdd(&Cb[(long)(rb + r) * LDC + cg], acc[mi][ni][r] * scale);
      }
    }
}

// ---------------------------------------------------------------------------
// convert1: t7 = bf16(c1 / 56), pad cols (jk%8==7) = 0.  float4 per thread.
// grid = NB*CC*CKP/4/256 = 4096
// ---------------------------------------------------------------------------
__global__ void convert1(const float* __restrict__ c1, u16* __restrict__ t7) {
  const int i = blockIdx.x * 256 + threadIdx.x;   // float4 idx over NB*CC*CKP/4
  float4 a = ((const float4*)c1)[i];
  const float s = 1.0f / 56.0f;
  u16 w3 = (i & 1) ? (u16)0 : f2bf(a.w * s);  // col%8==7 = elem3 of odd float4s
  ushort4 o = make_ushort4(f2bf(a.x * s), f2bf(a.y * s), f2bf(a.z * s), w3);
  ((ushort4*)t7)[i] = o;
}

// ---------------------------------------------------------------------------
// Pipeline: memset(c1,out) -> pass1 -> pass2 -> gemm1(atomic) -> convert1
//           -> pass3 -> gemm2(atomic -> d_out)
// Aliasing (stream-ordered): c1 (16.8 MB fp32) occupies the head of the t6T
// region; convert1 drains it before pass3 overwrites t6T.  Footprint 239.7 MB.
// ---------------------------------------------------------------------------
extern "C" void kernel_launch(void* const* d_in, const int* in_sizes, int n_in,
                              void* d_out, int out_size, void* d_ws, size_t ws_size,
                              hipStream_t stream) {
  const float* x   = (const float*)d_in[0];   // (8,256,56,56)
  const float* p1w = (const float*)d_in[1];   // (1,256,56,56)

  char* ws = (char*)d_ws;
  size_t o = 0;
  u16* xb  = (u16*)(ws + o); o += (size_t)NB * CC * HW * 2;   //  12.8 MB
  u16* t5  = (u16*)(ws + o); o += (size_t)NB * CKP * HW * 2;  // 102.8 MB
  u16* t6T = (u16*)(ws + o); o += (size_t)NB * HW * CKP * 2;  // 102.8 MB
  u16* t7  = (u16*)(ws + o); o += (size_t)NB * CC * CKP * 2;  //   8.4 MB
  u16* t1b = (u16*)(ws + o); o += (size_t)NB * CC * HW * 2;   //  12.8 MB
  float* c1 = (float*)t6T;   // NB*CC*CKP*4 = 16.8 MB <= 102.8, dead before pass3

  hipMemsetAsync(c1, 0, (size_t)NB * CC * CKP * 4, stream);
  hipMemsetAsync(d_out, 0, (size_t)NB * CC * HW * 4, stream);

  pass1<<<NB * CC * HW / 4 / 256, 256, 0, stream>>>(x, p1w, t1b, xb);
  pass2<<<NB * CC * HW / 8 / 256, 256, 0, stream>>>(t1b, t5);
  gemm_nt<1, KS1><<<dim3(2, CKP / 128, NB * KS1), 256, 0, stream>>>(xb, t5, c1);
  convert1<<<NB * CC * CKP / 4 / 256, 256, 0, stream>>>(c1, t7);
  pass3<<<dim3(HW / P3P, NB), 256, 0, stream>>>(x, t1b, t6T);
  gemm_nt<0, KS2><<<dim3(2, (HW + 127) / 128, NB * KS2), 256, 0, stream>>>(t7, t6T, (float*)d_out);
}

// Round 6
// 283.798 us; speedup vs baseline: 1.1563x; 1.1563x over previous
//
#include <hip/hip_runtime.h>

typedef unsigned short u16;
typedef __bf16 bf16x8 __attribute__((ext_vector_type(8)));
typedef float f32x4 __attribute__((ext_vector_type(4)));

#define HH  56
#define WW  56
#define HW  3136      // 56*56
#define CC  256
#define NB  8
#define CKP 2048      // c*7 padded to c*8 so each channel's 7 taps are one 16B chunk
#define KS1 4         // split-K factor GEMM1 (49 iters -> 12/12/12/13)
#define KS2 2         // split-K factor GEMM2 (32 iters -> 16/16)

// round-to-nearest-even fp32 -> bf16 (bit pattern)
__device__ __forceinline__ u16 f2bf(float f) {
  unsigned int u = __float_as_uint(f);
  u += 0x7fffu + ((u >> 16) & 1u);
  return (u16)(u >> 16);
}
__device__ __forceinline__ float bf2f(u16 v) {
  return __uint_as_float((unsigned)v << 16);
}

// async global->LDS, 16B per lane; LDS dest is wave-uniform base + lane*16
__device__ __forceinline__ void lds_load16(const void* g, void* l) {
  __builtin_amdgcn_global_load_lds(
      (const __attribute__((address_space(1))) void*)g,
      (__attribute__((address_space(3))) void*)l, 16, 0, 0);
}

// ---------------------------------------------------------------------------
// pass1: t1b = bf16(p1w * x), xb = bf16(x).  Fully coalesced float4 reads.
// grid = N*C*HW/4/256 = 6272 blocks
// ---------------------------------------------------------------------------
__global__ void pass1(const float* __restrict__ x, const float* __restrict__ p1w,
                      u16* __restrict__ t1b, u16* __restrict__ xb) {
  int i = blockIdx.x * 256 + threadIdx.x;        // over N*C*HW/4
  int cw = i % (CC * HW / 4);                    // p1w broadcast over n
  float4 xv = ((const float4*)x)[i];
  float4 wv = ((const float4*)p1w)[cw];
  uint2 xo = make_uint2((unsigned)f2bf(xv.x) | ((unsigned)f2bf(xv.y) << 16),
                        (unsigned)f2bf(xv.z) | ((unsigned)f2bf(xv.w) << 16));
  ((uint2*)xb)[i] = xo;
  uint2 to = make_uint2((unsigned)f2bf(xv.x * wv.x) | ((unsigned)f2bf(xv.y * wv.y) << 16),
                        (unsigned)f2bf(xv.z * wv.z) | ((unsigned)f2bf(xv.w * wv.w) << 16));
  ((uint2*)t1b)[i] = to;
}

// ---------------------------------------------------------------------------
// pass2 (vectorized, 8 p per thread):
//   t5[n][j*8+k][p] = bf16(t1[n,j,p] - t1[n,(j-1)%C, h, w+k-3 (0-pad)])
// Loads: 1 uint4 row chunk + up to 3 uint4 tap chunks; stores 7 uint4.
// pad rows j*8+7 untouched (finite poison; their t7 columns are zeroed).
// grid = N*C*HW/8/256 = 3136
// ---------------------------------------------------------------------------
__global__ void pass2(const u16* __restrict__ t1b, u16* __restrict__ t5) {
  int idx = blockIdx.x * 256 + threadIdx.x;   // over NB*CC*(HW/8)
  int pc  = idx % (HW / 8);
  int rem = idx / (HW / 8);                   // n*C + j
  int j   = rem & (CC - 1);
  int n   = rem >> 8;
  int p0  = pc * 8;
  int h   = p0 / WW;
  int w0  = p0 - h * WW;                      // multiple of 8
  int jm  = (j + CC - 1) & (CC - 1);
  const u16* t1n = t1b + (long)(n * CC) * HW;

  u16 a[8];
  *(uint4*)a = *(const uint4*)&t1n[(long)j * HW + p0];
  const u16* rowm = t1n + (long)jm * HW + h * WW;
  u16 b[24];
  *(uint4*)&b[8] = *(const uint4*)&rowm[w0];
  if (w0 > 0)  *(uint4*)&b[0]  = *(const uint4*)&rowm[w0 - 8];
  else { b[5] = 0; b[6] = 0; b[7] = 0; }      // only positions 5..7 are used
  if (w0 < WW - 8) *(uint4*)&b[16] = *(const uint4*)&rowm[w0 + 8];
  else { b[16] = 0; b[17] = 0; b[18] = 0; }   // only positions 16..18 used

  float af[8];
#pragma unroll
  for (int i = 0; i < 8; ++i) af[i] = bf2f(a[i]);
  float bf[14];                               // window positions 5..18
#pragma unroll
  for (int i = 0; i < 14; ++i) bf[i] = bf2f(b[i + 5]);

  u16* out = t5 + ((long)n * CKP + j * 8) * HW + p0;
#pragma unroll
  for (int k = 0; k < 7; ++k) {
    u16 v[8];
#pragma unroll
    for (int i = 0; i < 8; ++i) v[i] = f2bf(af[i] - bf[i + k]);
    *(uint4*)&out[(long)k * HW] = make_uint4(
        v[0] | ((unsigned)v[1] << 16), v[2] | ((unsigned)v[3] << 16),
        v[4] | ((unsigned)v[5] << 16), v[6] | ((unsigned)v[7] << 16));
  }
}

// ---------------------------------------------------------------------------
// pass3 (j-chunked LDS transpose): t6T[n][p][j*8+k] =
//   bf16(x[n,j,p] + t1[n,(j-1)%C,(h-1)%56,((w+1)%56)+k-3]),  slot 7 = 0.
// Block = 16 p-values; 4 chunks of 64 channels; tile 16x(512+8) u16 = 16.6 KB.
// Phase A: 16 lanes along p -> full 64B x lines.  Phase B: 256B-run writes.
// grid = (HW/16=196, NB)
// ---------------------------------------------------------------------------
#define P3P  16
#define P3S  (512 + 8)          // chunk-tile row stride in u16 (bank rot 4/row)
__global__ __launch_bounds__(256)
void pass3(const float* __restrict__ x, const u16* __restrict__ t1b,
           u16* __restrict__ t6T) {
  __shared__ u16 tile[P3P * P3S];   // 16.6 KB
  const int n  = blockIdx.y;
  const int p0 = blockIdx.x * P3P;
  const int t  = threadIdx.x;

  const int pl = t & 15, js = t >> 4;     // phase A mapping
  const int p  = p0 + pl;
  const int h  = p / WW, w = p - h * WW;
  const int h2 = (h + HH - 1) % HH;       // roll +1 on h: source row h-1
  const int w2 = (w + 1) % WW;            // roll -1 on w: source col w+1
  const float* xn = x   + (long)n * CC * HW;
  const u16* t1n  = t1b + (long)n * CC * HW;

  const int pp = t >> 4, cl = t & 15;     // phase B mapping

  for (int jc = 0; jc < 4; ++jc) {
    // ---- phase A: compute 64 channels into the tile ----
#pragma unroll
    for (int jo = 0; jo < 4; ++jo) {
      const int j  = jc * 64 + jo * 16 + js;
      const int jm = (j + CC - 1) & (CC - 1);
      const float xv  = xn[(long)j * HW + p];
      const u16* rowm = t1n + (long)jm * HW + h2 * WW;
      u16 v[8];
#pragma unroll
      for (int k = 0; k < 7; ++k) {
        int tap = w2 + k - 3;
        float t4v = ((unsigned)tap < (unsigned)WW) ? bf2f(rowm[tap]) : 0.f;
        v[k] = f2bf(xv + t4v);
      }
      v[7] = 0;
      *(uint4*)&tile[pl * P3S + (jo * 16 + js) * 8] = make_uint4(
          v[0] | ((unsigned)v[1] << 16), v[2] | ((unsigned)v[3] << 16),
          v[4] | ((unsigned)v[5] << 16), v[6] | ((unsigned)v[7] << 16));
    }
    __syncthreads();
    // ---- phase B: coalesced write-out of this chunk ----
    u16* outp = t6T + ((long)(n * HW + p0 + pp)) * CKP + jc * 512;
    const u16* srcp = &tile[pp * P3S];
#pragma unroll
    for (int ci = 0; ci < 4; ++ci) {
      int chunk = ci * 16 + cl;           // 64 chunks of 8 u16 per p-row
      *(uint4*)&outp[chunk * 8] = *(const uint4*)&srcp[chunk * 8];
    }
    __syncthreads();
  }
}

// ---------------------------------------------------------------------------
// Split-K NT GEMM, bf16 MFMA 16x16x32, 128x128 tile, BK=64, global_load_lds,
// XOR chunk swizzle.  Writes fp32 partials (no scale): Cp[ks][nb][M][LDC].
// (atomic variant measured R5: 16.7M L2 RMW serialized -> gemm 101us. partials
//  + separate reduce (R4) kept gemms off top-5 -> this is the proven shape.)
// IS1: A=xb(256x3136) B=t5(2048x3136), KS1 splits of 49 iters.
// !IS1: A=t7(256x2048) B=t6T(3136x2048), KS2 splits of 32 iters, col guard.
// grid = (2, N/128, NB*KS)
// ---------------------------------------------------------------------------
template <int IS1, int KS>
__global__ __launch_bounds__(256)
void gemm_nt(const u16* __restrict__ A, const u16* __restrict__ B,
             float* __restrict__ Cp) {
  constexpr int  LDA = IS1 ? HW : CKP;
  constexpr int  LDB = IS1 ? HW : CKP;
  constexpr int  NIT = IS1 ? HW / 64 : CKP / 64;   // 49 : 32 K-iterations
  constexpr int  LDC = IS1 ? CKP : HW;
  constexpr long sA  = IS1 ? (long)CC * HW : (long)CC * CKP;
  constexpr long sB  = IS1 ? (long)CKP * HW : (long)HW * CKP;
  constexpr long sC  = IS1 ? (long)CC * CKP : (long)CC * HW;

  __shared__ u16 As[128 * 64];
  __shared__ u16 Bs[128 * 64];

  const int z  = blockIdx.z;
  const int nb = z / KS, ks = z % KS;
  const int it0 = NIT * ks / KS, it1 = NIT * (ks + 1) / KS;
  const u16* Ab = A + nb * sA;
  const u16* Bb = B + nb * sB;
  const int m0 = blockIdx.x * 128, n0 = blockIdx.y * 128;
  const int t = threadIdx.x;
  const int lane = t & 63, wave = t >> 6;
  const int wm = wave & 1, wn = wave >> 1;     // 2x2 waves, 64x64 each
  const int lm = lane & 15, quad = lane >> 4;

  f32x4 acc[4][4];
#pragma unroll
  for (int a = 0; a < 4; ++a)
#pragma unroll
    for (int b = 0; b < 4; ++b) acc[a][b] = (f32x4)0.0f;

  // staging geometry: 1024 chunks of 16B per tile, 4 per thread.
  int rowc[4], colc[4];
#pragma unroll
  for (int ci = 0; ci < 4; ++ci) {
    int c = t + ci * 256;
    rowc[ci] = c >> 3;
    colc[ci] = ((c & 7) ^ (rowc[ci] & 7)) * 8;   // XOR swizzle breaks bank aliasing
  }

  for (int it = it0; it < it1; ++it) {
    const int k0 = it * 64;
#pragma unroll
    for (int ci = 0; ci < 4; ++ci) {
      int c = t + ci * 256;
      lds_load16(Ab + (long)(m0 + rowc[ci]) * LDA + k0 + colc[ci], &As[c * 8]);
      int br = n0 + rowc[ci];
      if (!IS1) br = br < (HW - 1) ? br : (HW - 1);   // clamp rows past 3135
      lds_load16(Bb + (long)br * LDB + k0 + colc[ci], &Bs[c * 8]);
    }
    __syncthreads();
#pragma unroll
    for (int kk = 0; kk < 2; ++kk) {
      const int phys = ((kk * 4 + quad) ^ (lm & 7)) * 8;  // swizzled chunk, elems
      bf16x8 af[4], bv[4];
#pragma unroll
      for (int mi = 0; mi < 4; ++mi)
        af[mi] = *(const bf16x8*)&As[(wm * 64 + mi * 16 + lm) * 64 + phys];
#pragma unroll
      for (int ni = 0; ni < 4; ++ni)
        bv[ni] = *(const bf16x8*)&Bs[(wn * 64 + ni * 16 + lm) * 64 + phys];
#pragma unroll
      for (int mi = 0; mi < 4; ++mi)
#pragma unroll
        for (int ni = 0; ni < 4; ++ni)
          acc[mi][ni] = __builtin_amdgcn_mfma_f32_16x16x32_bf16(
              af[mi], bv[ni], acc[mi][ni], 0, 0, 0);
    }
    __syncthreads();
  }

  // epilogue: fp32 partial store; C/D layout: col = lane&15, row = quad*4+reg
  float* Cb = Cp + ((long)ks * NB + nb) * sC;
#pragma unroll
  for (int mi = 0; mi < 4; ++mi)
#pragma unroll
    for (int ni = 0; ni < 4; ++ni) {
      int rb = m0 + wm * 64 + mi * 16 + quad * 4;
      int cg = n0 + wn * 64 + ni * 16 + lm;
      if (IS1 || cg < HW) {
#pragma unroll
        for (int r = 0; r < 4; ++r)
          Cb[(long)(rb + r) * LDC + cg] = acc[mi][ni][r];
      }
    }
}

// ---------------------------------------------------------------------------
// reduce1: t7 = bf16((sum of KS1 partials) / 56), pad cols (jk%8==7) = 0.
// float4 per thread.  grid = NB*CC*CKP/4/256 = 4096
// ---------------------------------------------------------------------------
__global__ void reduce1(const float* __restrict__ p1, u16* __restrict__ t7) {
  const int i = blockIdx.x * 256 + threadIdx.x;   // float4 idx over NB*CC*CKP/4
  const long S = (long)NB * CC * CKP / 4;
  float4 a = ((const float4*)p1)[i];
  float4 b = ((const float4*)p1)[i + S];
  float4 c = ((const float4*)p1)[i + 2 * S];
  float4 d = ((const float4*)p1)[i + 3 * S];
  const float s = 1.0f / 56.0f;
  float e0 = (a.x + b.x + c.x + d.x) * s;
  float e1 = (a.y + b.y + c.y + d.y) * s;
  float e2 = (a.z + b.z + c.z + d.z) * s;
  float e3 = (a.w + b.w + c.w + d.w) * s;
  u16 w3 = (i & 1) ? (u16)0 : f2bf(e3);   // col%8==7 lives at elem3 of odd float4s
  ushort4 o = make_ushort4(f2bf(e0), f2bf(e1), f2bf(e2), w3);
  ((ushort4*)t7)[i] = o;
}

// ---------------------------------------------------------------------------
// reduce2: d_out = (sum of KS2 partials) / sqrt(1792).  fp32 float4.
// grid = NB*CC*HW/4/256 = 6272
// ---------------------------------------------------------------------------
__global__ void reduce2(const float* __restrict__ p2, float* __restrict__ out) {
  const int i = blockIdx.x * 256 + threadIdx.x;   // float4 idx over NB*CC*HW/4
  const long S = (long)NB * CC * HW / 4;
  float4 a = ((const float4*)p2)[i];
  float4 b = ((const float4*)p2)[i + S];
  const float s = 0.023622783f;
  float4 o;
  o.x = (a.x + b.x) * s; o.y = (a.y + b.y) * s;
  o.z = (a.z + b.z) * s; o.w = (a.w + b.w) * s;
  ((float4*)out)[i] = o;
}

// ---------------------------------------------------------------------------
// Pipeline: pass1 -> pass2 -> gemm1 -> reduce1 -> pass3 -> gemm2 -> reduce2
// Aliasing (stream-ordered, proven ws bound 252.4 MB; footprint 239.7 MB):
//   p1 (67.1 MB fp32 partials) aliases t6T region (drained before pass3)
//   p2 (51.4 MB fp32 partials) aliases t5 region (dead after gemm1)
// ---------------------------------------------------------------------------
extern "C" void kernel_launch(void* const* d_in, const int* in_sizes, int n_in,
                              void* d_out, int out_size, void* d_ws, size_t ws_size,
                              hipStream_t stream) {
  const float* x   = (const float*)d_in[0];   // (8,256,56,56)
  const float* p1w = (const float*)d_in[1];   // (1,256,56,56)

  char* ws = (char*)d_ws;
  size_t o = 0;
  u16* xb  = (u16*)(ws + o); o += (size_t)NB * CC * HW * 2;   //  12.8 MB
  u16* t5  = (u16*)(ws + o); o += (size_t)NB * CKP * HW * 2;  // 102.8 MB
  u16* t6T = (u16*)(ws + o); o += (size_t)NB * HW * CKP * 2;  // 102.8 MB
  u16* t7  = (u16*)(ws + o); o += (size_t)NB * CC * CKP * 2;  //   8.4 MB
  u16* t1b = (u16*)(ws + o); o += (size_t)NB * CC * HW * 2;   //  12.8 MB
  float* p1 = (float*)t6T;   // KS1*NB*CC*CKP*4 = 67.1 MB <= 102.8
  float* p2 = (float*)t5;    // KS2*NB*CC*HW*4  = 51.4 MB <= 102.8

  pass1<<<NB * CC * HW / 4 / 256, 256, 0, stream>>>(x, p1w, t1b, xb);
  pass2<<<NB * CC * HW / 8 / 256, 256, 0, stream>>>(t1b, t5);
  gemm_nt<1, KS1><<<dim3(2, CKP / 128, NB * KS1), 256, 0, stream>>>(xb, t5, p1);
  reduce1<<<NB * CC * CKP / 4 / 256, 256, 0, stream>>>(p1, t7);
  pass3<<<dim3(HW / P3P, NB), 256, 0, stream>>>(x, t1b, t6T);
  gemm_nt<0, KS2><<<dim3(2, (HW + 127) / 128, NB * KS2), 256, 0, stream>>>(t7, t6T, p2);
  reduce2<<<NB * CC * HW / 4 / 256, 256, 0, stream>>>(p2, (float*)d_out);
}

// Round 7
// 210.204 us; speedup vs baseline: 1.5611x; 1.3501x over previous
//
#include <hip/hip_runtime.h>

typedef unsigned short u16;
typedef __bf16 bf16x8 __attribute__((ext_vector_type(8)));
typedef float f32x4 __attribute__((ext_vector_type(4)));

#define HH  56
#define WW  56
#define HW  3136      // 56*56
#define CC  256
#define NB  8
#define CKP 2048      // c*7 padded to c*8: channel j's taps = cols j*8..j*8+7
#define KS1 4         // split-K factor GEMM1 (49 iters -> 12/12/12/13)

// round-to-nearest-even fp32 -> bf16 (bit pattern)
__device__ __forceinline__ u16 f2bf(float f) {
  unsigned int u = __float_as_uint(f);
  u += 0x7fffu + ((u >> 16) & 1u);
  return (u16)(u >> 16);
}
__device__ __forceinline__ float bf2f(u16 v) {
  return __uint_as_float((unsigned)v << 16);
}

// async global->LDS, 16B per lane; LDS dest is wave-uniform base + lane*16
__device__ __forceinline__ void lds_load16(const void* g, void* l) {
  __builtin_amdgcn_global_load_lds(
      (const __attribute__((address_space(1))) void*)g,
      (__attribute__((address_space(3))) void*)l, 16, 0, 0);
}

// ---------------------------------------------------------------------------
// pass1: t1b = bf16(p1w * x), xb = bf16(x).  Fully coalesced float4 reads.
// grid = N*C*HW/4/256 = 6272
// ---------------------------------------------------------------------------
__global__ void pass1(const float* __restrict__ x, const float* __restrict__ p1w,
                      u16* __restrict__ t1b, u16* __restrict__ xb) {
  int i = blockIdx.x * 256 + threadIdx.x;        // over N*C*HW/4
  int cw = i % (CC * HW / 4);                    // p1w broadcast over n
  float4 xv = ((const float4*)x)[i];
  float4 wv = ((const float4*)p1w)[cw];
  uint2 xo = make_uint2((unsigned)f2bf(xv.x) | ((unsigned)f2bf(xv.y) << 16),
                        (unsigned)f2bf(xv.z) | ((unsigned)f2bf(xv.w) << 16));
  ((uint2*)xb)[i] = xo;
  uint2 to = make_uint2((unsigned)f2bf(xv.x * wv.x) | ((unsigned)f2bf(xv.y * wv.y) << 16),
                        (unsigned)f2bf(xv.z * wv.z) | ((unsigned)f2bf(xv.w * wv.w) << 16));
  ((uint2*)t1b)[i] = to;
}

// ---------------------------------------------------------------------------
// gemm1f: fused t5-generation NT GEMM (split-K), 128x128 tile, BK=64.
//   C[i][j*8+k] = sum_p xb[i,p] * (t1[j,p] - pad(t1[(j-1)%C, p+k-3]))
// A = xb staged via global_load_lds; B generated into LDS from t1b windows.
// B-gen map: 256 thr -> (jl=(t>>3)&15, pc=t&7, hf=t>>7); hf0: k=0..3,
// hf1: k=4..6 + pad row (zeros).  Static window indices (pass2's scheme).
// Writes fp32 partials Cp[ks][nb][256][CKP].  grid = (2, 16, NB*KS1)
// ---------------------------------------------------------------------------
__global__ __launch_bounds__(256)
void gemm1f(const u16* __restrict__ A, const u16* __restrict__ t1b,
            float* __restrict__ Cp) {
  __shared__ u16 As[128 * 64];
  __shared__ u16 Bs[128 * 64];

  const int z = blockIdx.z, nb = z / KS1, ks = z % KS1;
  const int it0 = 49 * ks / KS1, it1 = 49 * (ks + 1) / KS1;
  const u16* Ab  = A   + (long)nb * CC * HW;
  const u16* t1n = t1b + (long)nb * CC * HW;
  const int m0 = blockIdx.x * 128, n0 = blockIdx.y * 128;
  const int jb = blockIdx.y * 16;                 // first channel of tile
  const int t = threadIdx.x;
  const int lane = t & 63, wave = t >> 6;
  const int wm = wave & 1, wn = wave >> 1;        // 2x2 waves, 64x64 each
  const int lm = lane & 15, quad = lane >> 4;

  // B-gen mapping
  const int jl = (t >> 3) & 15, pc = t & 7, hf = t >> 7;
  const int j  = jb + jl;
  const int jm = (j + CC - 1) & (CC - 1);
  const u16* arow = t1n + (long)j  * HW;
  const u16* wrow = t1n + (long)jm * HW;

  f32x4 acc[4][4];
#pragma unroll
  for (int a = 0; a < 4; ++a)
#pragma unroll
    for (int b = 0; b < 4; ++b) acc[a][b] = (f32x4)0.0f;

  // A staging geometry: 1024 chunks of 16B, 4 per thread
  int rowc[4], colc[4];
#pragma unroll
  for (int ci = 0; ci < 4; ++ci) {
    int c = t + ci * 256;
    rowc[ci] = c >> 3;
    colc[ci] = ((c & 7) ^ (rowc[ci] & 7)) * 8;
  }

  for (int it = it0; it < it1; ++it) {
    const int k0 = it * 64;
#pragma unroll
    for (int ci = 0; ci < 4; ++ci)
      lds_load16(Ab + (long)(m0 + rowc[ci]) * HW + k0 + colc[ci],
                 &As[(t + ci * 256) * 8]);

    // ---- B-gen: 8 p-values (p8..p8+7), rows jl*8+k ----
    {
      const int p8 = k0 + pc * 8;
      u16 Ar[8], Wd[24];                       // window = flat [p8-8, p8+16)
      *(uint4*)Ar = *(const uint4*)&arow[p8];
#pragma unroll
      for (int L = 0; L < 3; ++L) {
        int ad = p8 - 8 + L * 8;
        ad = ad < 0 ? 0 : (ad > HW - 8 ? HW - 8 : ad);  // garbage only at masked idx
        *(uint4*)&Wd[L * 8] = *(const uint4*)&wrow[ad];
      }
      int w0t = p8 % 56;
      float Af[8];
#pragma unroll
      for (int e = 0; e < 8; ++e) Af[e] = bf2f(Ar[e]);
      if (hf == 0) {                           // k = 0..3
#pragma unroll
        for (int k = 0; k < 4; ++k) {
          u16 v[8];
#pragma unroll
          for (int e = 0; e < 8; ++e) {
            int w = w0t + e; if (w >= 56) w -= 56;
            float tap = ((unsigned)(w + k - 3) < 56u) ? bf2f(Wd[e + k + 5]) : 0.f;
            v[e] = f2bf(Af[e] - tap);
          }
          *(uint4*)&Bs[(jl * 8 + k) * 64 + (pc ^ k) * 8] = make_uint4(
              v[0] | ((unsigned)v[1] << 16), v[2] | ((unsigned)v[3] << 16),
              v[4] | ((unsigned)v[5] << 16), v[6] | ((unsigned)v[7] << 16));
        }
      } else {                                 // k = 4..6 + pad row 7
#pragma unroll
        for (int k = 4; k < 7; ++k) {
          u16 v[8];
#pragma unroll
          for (int e = 0; e < 8; ++e) {
            int w = w0t + e; if (w >= 56) w -= 56;
            float tap = ((unsigned)(w + k - 3) < 56u) ? bf2f(Wd[e + k + 5]) : 0.f;
            v[e] = f2bf(Af[e] - tap);
          }
          *(uint4*)&Bs[(jl * 8 + k) * 64 + (pc ^ k) * 8] = make_uint4(
              v[0] | ((unsigned)v[1] << 16), v[2] | ((unsigned)v[3] << 16),
              v[4] | ((unsigned)v[5] << 16), v[6] | ((unsigned)v[7] << 16));
        }
        *(uint4*)&Bs[(jl * 8 + 7) * 64 + (pc ^ 7) * 8] = make_uint4(0, 0, 0, 0);
      }
    }
    __syncthreads();
#pragma unroll
    for (int kk = 0; kk < 2; ++kk) {
      const int phys = ((kk * 4 + quad) ^ (lm & 7)) * 8;
      bf16x8 af[4], bv[4];
#pragma unroll
      for (int mi = 0; mi < 4; ++mi)
        af[mi] = *(const bf16x8*)&As[(wm * 64 + mi * 16 + lm) * 64 + phys];
#pragma unroll
      for (int ni = 0; ni < 4; ++ni)
        bv[ni] = *(const bf16x8*)&Bs[(wn * 64 + ni * 16 + lm) * 64 + phys];
#pragma unroll
      for (int mi = 0; mi < 4; ++mi)
#pragma unroll
        for (int ni = 0; ni < 4; ++ni)
          acc[mi][ni] = __builtin_amdgcn_mfma_f32_16x16x32_bf16(
              af[mi], bv[ni], acc[mi][ni], 0, 0, 0);
    }
    __syncthreads();
  }

  // fp32 partial store; C/D layout: col = lane&15, row = quad*4 + reg
  float* Cb = Cp + ((long)ks * NB + nb) * (long)CC * CKP;
#pragma unroll
  for (int mi = 0; mi < 4; ++mi)
#pragma unroll
    for (int ni = 0; ni < 4; ++ni) {
      int rb = m0 + wm * 64 + mi * 16 + quad * 4;
      int cg = n0 + wn * 64 + ni * 16 + lm;
#pragma unroll
      for (int r = 0; r < 4; ++r)
        Cb[(long)(rb + r) * CKP + cg] = acc[mi][ni][r];
    }
}

// ---------------------------------------------------------------------------
// reduce1: t7 = bf16((sum of KS1 partials) / 56), pad cols (jk%8==7) = 0.
// grid = NB*CC*CKP/4/256 = 4096
// ---------------------------------------------------------------------------
__global__ void reduce1(const float* __restrict__ p1, u16* __restrict__ t7) {
  const int i = blockIdx.x * 256 + threadIdx.x;
  const long S = (long)NB * CC * CKP / 4;
  float4 a = ((const float4*)p1)[i];
  float4 b = ((const float4*)p1)[i + S];
  float4 c = ((const float4*)p1)[i + 2 * S];
  float4 d = ((const float4*)p1)[i + 3 * S];
  const float s = 1.0f / 56.0f;
  float e0 = (a.x + b.x + c.x + d.x) * s;
  float e1 = (a.y + b.y + c.y + d.y) * s;
  float e2 = (a.z + b.z + c.z + d.z) * s;
  float e3 = (a.w + b.w + c.w + d.w) * s;
  u16 w3 = (i & 1) ? (u16)0 : f2bf(e3);   // col%8==7 = elem3 of odd float4s
  ushort4 o = make_ushort4(f2bf(e0), f2bf(e1), f2bf(e2), w3);
  ((ushort4*)t7)[i] = o;
}

// ---------------------------------------------------------------------------
// gemm2f: fused t6T-generation NT GEMM, 128x64 tile, BK=64, NO split-K.
//   out[i][p] = s2 * sum_{j,k} t7[i][j*8+k] * (x[j,p] + pad(t1[(j-1)%C, roll(p)+k-3]))
// A = t7 staged via global_load_lds; B (64 p-rows x 64 jk) generated from
// x + rolled t1b taps (pass3's math).  49*64 = 3136 -> no col guard.
// grid = (2, 49, NB)
// ---------------------------------------------------------------------------
__global__ __launch_bounds__(256)
void gemm2f(const u16* __restrict__ A, const float* __restrict__ x,
            const u16* __restrict__ t1b, float* __restrict__ out) {
  __shared__ u16 As[128 * 64];
  __shared__ u16 Bs[64 * 64];

  const int nb = blockIdx.z;
  const u16* Ab   = A   + (long)nb * CC * CKP;
  const float* xn = x   + (long)nb * CC * HW;
  const u16* t1n  = t1b + (long)nb * CC * HW;
  const int m0 = blockIdx.x * 128, n0 = blockIdx.y * 64;
  const int t = threadIdx.x;
  const int lane = t & 63, wave = t >> 6;
  const int wm = wave & 1, wn = wave >> 1;        // 2(m) x 2(n of 32)
  const int lm = lane & 15, quad = lane >> 4;

  // B-gen mapping: pr = p-row, jg -> 2 channels per thread per iter
  const int pr = t & 63, jg = t >> 6;
  const int p  = n0 + pr;
  const int h  = p / WW, w = p - h * WW;
  const int h2 = (h + HH - 1) % HH;               // roll +1 on h
  const int w2 = (w + 1) % WW;                    // roll -1 on w
  const int swz = pr & 7;

  f32x4 acc[4][2];
#pragma unroll
  for (int a = 0; a < 4; ++a)
#pragma unroll
    for (int b = 0; b < 2; ++b) acc[a][b] = (f32x4)0.0f;

  int rowc[4], colc[4];
#pragma unroll
  for (int ci = 0; ci < 4; ++ci) {
    int c = t + ci * 256;
    rowc[ci] = c >> 3;
    colc[ci] = ((c & 7) ^ (rowc[ci] & 7)) * 8;
  }

  for (int it = 0; it < 32; ++it) {
    const int k0 = it * 64;
#pragma unroll
    for (int ci = 0; ci < 4; ++ci)
      lds_load16(Ab + (long)(m0 + rowc[ci]) * CKP + k0 + colc[ci],
                 &As[(t + ci * 256) * 8]);

    // ---- B-gen: 2 channels, one uint4 each ----
#pragma unroll
    for (int jj = 0; jj < 2; ++jj) {
      const int jch = it * 8 + jg * 2 + jj;
      const int jmm = (jch + CC - 1) & (CC - 1);
      const float xv = xn[(long)jch * HW + p];
      const u16* trow = t1n + (long)jmm * HW + h2 * WW;
      u16 v[8];
#pragma unroll
      for (int k = 0; k < 7; ++k) {
        int ww = w2 + k - 3;
        int wc = ww < 0 ? 0 : (ww > 55 ? 55 : ww);     // clamped, in-bounds
        float tv = bf2f(trow[wc]);
        float tap = ((unsigned)ww < 56u) ? tv : 0.f;
        v[k] = f2bf(xv + tap);
      }
      v[7] = 0;   // pad slot MUST be finite (A pad col is exact 0)
      *(uint4*)&Bs[pr * 64 + (((jg * 2 + jj) ^ swz) * 8)] = make_uint4(
          v[0] | ((unsigned)v[1] << 16), v[2] | ((unsigned)v[3] << 16),
          v[4] | ((unsigned)v[5] << 16), v[6] | ((unsigned)v[7] << 16));
    }
    __syncthreads();
#pragma unroll
    for (int kk = 0; kk < 2; ++kk) {
      const int phys = ((kk * 4 + quad) ^ (lm & 7)) * 8;
      bf16x8 af[4], bv[2];
#pragma unroll
      for (int mi = 0; mi < 4; ++mi)
        af[mi] = *(const bf16x8*)&As[(wm * 64 + mi * 16 + lm) * 64 + phys];
#pragma unroll
      for (int ni = 0; ni < 2; ++ni)
        bv[ni] = *(const bf16x8*)&Bs[(wn * 32 + ni * 16 + lm) * 64 + phys];
#pragma unroll
      for (int mi = 0; mi < 4; ++mi)
#pragma unroll
        for (int ni = 0; ni < 2; ++ni)
          acc[mi][ni] = __builtin_amdgcn_mfma_f32_16x16x32_bf16(
              af[mi], bv[ni], acc[mi][ni], 0, 0, 0);
    }
    __syncthreads();
  }

  const float s2 = 0.023622783f;                  // 1/sqrt(1792)
  float* Ob = out + (long)nb * CC * HW;
#pragma unroll
  for (int mi = 0; mi < 4; ++mi)
#pragma unroll
    for (int ni = 0; ni < 2; ++ni) {
      int rb = m0 + wm * 64 + mi * 16 + quad * 4;
      int cg = n0 + wn * 32 + ni * 16 + lm;       // < 3136 always (49*64)
#pragma unroll
      for (int r = 0; r < 4; ++r)
        Ob[(long)(rb + r) * HW + cg] = acc[mi][ni][r] * s2;
    }
}

// ---------------------------------------------------------------------------
// Pipeline: pass1 -> gemm1f -> reduce1 -> gemm2f.   Footprint ~101 MB.
// ---------------------------------------------------------------------------
extern "C" void kernel_launch(void* const* d_in, const int* in_sizes, int n_in,
                              void* d_out, int out_size, void* d_ws, size_t ws_size,
                              hipStream_t stream) {
  const float* x   = (const float*)d_in[0];   // (8,256,56,56)
  const float* p1w = (const float*)d_in[1];   // (1,256,56,56)

  char* ws = (char*)d_ws;
  size_t o = 0;
  u16* xb  = (u16*)(ws + o); o += (size_t)NB * CC * HW * 2;          //  12.8 MB
  u16* t1b = (u16*)(ws + o); o += (size_t)NB * CC * HW * 2;          //  12.8 MB
  u16* t7  = (u16*)(ws + o); o += (size_t)NB * CC * CKP * 2;         //   8.4 MB
  float* p1 = (float*)(ws + o); o += (size_t)KS1 * NB * CC * CKP * 4; // 67.1 MB

  pass1<<<NB * CC * HW / 4 / 256, 256, 0, stream>>>(x, p1w, t1b, xb);
  gemm1f<<<dim3(2, 16, NB * KS1), 256, 0, stream>>>(xb, t1b, p1);
  reduce1<<<NB * CC * CKP / 4 / 256, 256, 0, stream>>>(p1, t7);
  gemm2f<<<dim3(2, 49, NB), 256, 0, stream>>>(t7, x, t1b, (float*)d_out);
}